// Round 5
// baseline (228.502 us; speedup 1.0000x reference)
//
#include <hip/hip_runtime.h>
#include <math.h>

#define B_ 512
#define C_ 100
#define E_ 2048
#define F_ 128

typedef _Float16 f16x8 __attribute__((ext_vector_type(8)));
typedef float    f32x4 __attribute__((ext_vector_type(4)));
typedef float    f32x2 __attribute__((ext_vector_type(2)));

#define AS1q __attribute__((address_space(1)))
#define AS3q __attribute__((address_space(3)))

// async global->LDS DMA, 16 B per lane; LDS dest = wave-uniform base + lane*16
__device__ __forceinline__ void gl_lds16(const void* g, void* lds_base) {
    __builtin_amdgcn_global_load_lds((const AS1q void*)g, (AS3q void*)lds_base, 16, 0, 0);
}

// MFMA A/B fragment from swizzled fp32 tile (128 rows x 64 floats): logical
// 16B-chunk g of row r lives at slot g^(r&15). Fragment (row r, pair p) =
// floats [p*8, p*8+8). fp32->fp16 cvt in registers. (verified round-0)
__device__ __forceinline__ f16x8 frag_ld(const float* T, int r, int p) {
    const int k = r & 15;
    const int b = r << 6;
    const f32x4 lo = *(const f32x4*)&T[b + ((((p << 1))     ^ k) << 2)];
    const f32x4 hi = *(const f32x4*)&T[b + ((((p << 1) | 1) ^ k) << 2)];
    f16x8 fr;
    fr[0] = (_Float16)lo[0]; fr[1] = (_Float16)lo[1];
    fr[2] = (_Float16)lo[2]; fr[3] = (_Float16)lo[3];
    fr[4] = (_Float16)hi[0]; fr[5] = (_Float16)hi[1];
    fr[6] = (_Float16)hi[2]; fr[7] = (_Float16)hi[3];
    return fr;
}

// ---------------- kernel 1 (tiny): x fp32 -> fp16
__global__ __launch_bounds__(256, 8)
void k_prep(const float* __restrict__ x, _Float16* __restrict__ xh) {
    const size_t base = (size_t)blockIdx.x * 8192 + (size_t)threadIdx.x * 8;
#pragma unroll
    for (int it = 0; it < 4; ++it) {
        const size_t idx = base + (size_t)it * 2048;
        float4 a  = *(const float4*)(x + idx);
        float4 bb = *(const float4*)(x + idx + 4);
        f16x8 h;
        h[0] = (_Float16)a.x;  h[1] = (_Float16)a.y;  h[2] = (_Float16)a.z;  h[3] = (_Float16)a.w;
        h[4] = (_Float16)bb.x; h[5] = (_Float16)bb.y; h[6] = (_Float16)bb.z; h[7] = (_Float16)bb.w;
        *(f16x8*)(xh + idx) = h;
    }
}

// ---------------- kernel 2: FULLY FUSED. Per (class, b-tile) block:
//   K-loop over all E: DMA W fp32 tile (swizzled) + xh fp16 tile;
//   phase1: A1 (v[e]=sum_f W u, fp32 VALU) || GEMM 32 MFMA (frag cvt for W);
//   phase2: y += W v via 8 MFMA REUSING the bv fragments (v as B-col-0).
//   Epilogue: sigma from local y (u.y / y.y); dist2 + exp.
// No Wh intermediate (saves 104 MB HBM round-trip), no kernel serialization.
// Round-3 XCD map: 4 sibling b-tiles of a class on ONE XCD -> W via L2.
__global__ __launch_bounds__(256, 2)
void k_fused(const float* __restrict__ W, const _Float16* __restrict__ xh,
             const float* __restrict__ bias, const float* __restrict__ cent,
             const float* __restrict__ u, float* __restrict__ out) {
    const int bid  = blockIdx.x;
    const int xcd  = bid & 7;
    const int slot = bid >> 3;
    const int c    = xcd * 13 + (slot >> 2);
    if (c >= C_) return;                       // uniform early-out (16 blocks)
    const int b0 = (slot & 3) * 128;

    const int t  = threadIdx.x;
    const int w  = t >> 6;
    const int l  = t & 63;
    const int wm = w & 1, wn = w >> 1;
    const int ln = l & 15, quad = l >> 4;

    __shared__ float    Ts[128 * 64];   // 32 KB fp32 W tile (16-slot swizzle)
    __shared__ _Float16 Xs[128 * 64];   // 16 KB fp16 x tile (8-slot swizzle)
    __shared__ float    vs[64];         // v for current e-window
    __shared__ float    ys[128];        // final y
    __shared__ float    red2[2][2];
    __shared__ float    s_rsig;

    // ---- accumulators
    f32x4 acc[4][4];
#pragma unroll
    for (int mt = 0; mt < 4; ++mt)
#pragma unroll
        for (int nt = 0; nt < 4; ++nt) acc[mt][nt] = (f32x4){0.f, 0.f, 0.f, 0.f};
    f32x4 y_acc[4];
#pragma unroll
    for (int nt = 0; nt < 4; ++nt) y_acc[nt] = (f32x4){0.f, 0.f, 0.f, 0.f};

    // ---- staging constants
    const int lrow4 = l >> 4, cs = l & 15;
    const float* wbase = W + (size_t)c * F_ * E_;
    const int lr = l >> 3;
    const int lg = (l & 7) ^ lr;
    const _Float16* xsrc = xh + (size_t)(b0 + w * 32 + lr) * E_ + lg * 8;

    // ---- A1 constants: thread handles e-pair p (e = 2p, 2p+1), rows sub*16..+16
    const int p_  = t >> 3;
    const int sub = t & 7;
    const int gA  = p_ >> 1;               // chunk of e-pair
    const int wiA = (p_ & 1) * 2;          // float offset within chunk
    float ur[16];
#pragma unroll
    for (int j = 0; j < 16; ++j) ur[j] = u[(size_t)c * F_ + sub * 16 + j];

    // ---- epilogue constants (latency hidden under K-loop)
    float bi[4], ce[4];
#pragma unroll
    for (int nt = 0; nt < 4; ++nt) {
        int f = wn * 64 + nt * 16 + ln;
        bi[nt] = bias[c * F_ + f];
        ce[nt] = cent[c * F_ + f];
    }

    for (int k0 = 0; k0 < E_; k0 += 64) {
        // ---- stage: W fp32 (8 DMA/wave, k_gram pattern) + x fp16 (4 DMA/wave)
#pragma unroll
        for (int qq = 0; qq < 8; ++qq) {
            const int q   = w * 8 + qq;
            const int r   = q * 4 + lrow4;
            const int off = ((cs ^ (r & 15)) << 2);
            gl_lds16(wbase + (size_t)r * E_ + k0 + off, &Ts[q * 256]);
        }
#pragma unroll
        for (int q = 0; q < 4; ++q)
            gl_lds16(xsrc + (size_t)q * 8 * E_ + k0, &Xs[(w * 4 + q) * 512]);
        __syncthreads();   // barrier A: tiles ready; prev v_frag reads done

        // ---- phase 1a: A1  v[e] = sum_f W[f,e] u[f]  (fp32, b64 column reads)
        {
            float p0 = 0.f, p1 = 0.f;
#pragma unroll
            for (int j = 0; j < 16; ++j) {
                const int f = sub * 16 + j;
                const f32x2 wv = *(const f32x2*)&Ts[(f << 6) + ((gA ^ (f & 15)) << 2) + wiA];
                p0 = fmaf(wv[0], ur[j], p0);
                p1 = fmaf(wv[1], ur[j], p1);
            }
            p0 += __shfl_xor(p0, 1, 64); p1 += __shfl_xor(p1, 1, 64);
            p0 += __shfl_xor(p0, 2, 64); p1 += __shfl_xor(p1, 2, 64);
            p0 += __shfl_xor(p0, 4, 64); p1 += __shfl_xor(p1, 4, 64);
            if (sub == 0) { vs[2 * p_] = p0; vs[2 * p_ + 1] = p1; }
        }

        // ---- phase 1b: GEMM MFMA (bv kept across kh for phase 2 reuse)
        f16x8 bv[2][4];
#pragma unroll
        for (int kh = 0; kh < 2; ++kh) {
            const int g0 = kh * 4 + quad;
            const int sw = (g0 ^ (ln & 7)) * 8;
            f16x8 av[4];
#pragma unroll
            for (int mt = 0; mt < 4; ++mt)
                av[mt] = *(const f16x8*)&Xs[(wm * 64 + mt * 16 + ln) * 64 + sw];
#pragma unroll
            for (int nt = 0; nt < 4; ++nt)
                bv[kh][nt] = frag_ld(Ts, wn * 64 + nt * 16 + ln, g0);
#pragma unroll
            for (int mt = 0; mt < 4; ++mt)
#pragma unroll
                for (int nt = 0; nt < 4; ++nt)
                    acc[mt][nt] = __builtin_amdgcn_mfma_f32_16x16x32_f16(
                        av[mt], bv[kh][nt], acc[mt][nt], 0, 0, 0);
        }
        __syncthreads();   // barrier B: vs ready; all tile reads done

        // ---- phase 2: y += W v  (v as B col 0; W rows from bv regs as A)
#pragma unroll
        for (int kh = 0; kh < 2; ++kh) {
            f16x8 vf;
#pragma unroll
            for (int j = 0; j < 8; ++j) vf[j] = (_Float16)0.0f;
            if (ln == 0) {
                const float* vp = &vs[kh * 32 + quad * 8];
                const f32x4 a  = *(const f32x4*)vp;
                const f32x4 bq = *(const f32x4*)(vp + 4);
                vf[0] = (_Float16)a[0];  vf[1] = (_Float16)a[1];
                vf[2] = (_Float16)a[2];  vf[3] = (_Float16)a[3];
                vf[4] = (_Float16)bq[0]; vf[5] = (_Float16)bq[1];
                vf[6] = (_Float16)bq[2]; vf[7] = (_Float16)bq[3];
            }
#pragma unroll
            for (int nt = 0; nt < 4; ++nt)
                y_acc[nt] = __builtin_amdgcn_mfma_f32_16x16x32_f16(
                    bv[kh][nt], vf, y_acc[nt], 0, 0, 0);
        }
    }

    // ---- sigma: y lives in col 0 of y_acc (D: col=ln, row=quad*4+r)
    if (wm == 0 && ln == 0) {
#pragma unroll
        for (int nt = 0; nt < 4; ++nt)
#pragma unroll
            for (int r = 0; r < 4; ++r)
                ys[wn * 64 + nt * 16 + quad * 4 + r] = y_acc[nt][r];
    }
    __syncthreads();
    if (t < 128) {
        float yf  = ys[t];
        float nvp = u[(size_t)c * F_ + t] * yf;
        float tsp = yf * yf;
        for (int off = 32; off; off >>= 1) {
            nvp += __shfl_down(nvp, off, 64);
            tsp += __shfl_down(tsp, off, 64);
        }
        if (l == 0) { red2[w][0] = nvp; red2[w][1] = tsp; }
    }
    __syncthreads();
    if (t == 0) s_rsig = sqrtf((red2[0][0] + red2[1][0]) / (red2[0][1] + red2[1][1]));
    __syncthreads();
    const float rsigma = s_rsig;

    // ---- dist2 + exp epilogue (round-3 verified, BM=128)
    float* red = (float*)&Xs[0];        // [128][2] floats, post-loop reuse

#pragma unroll
    for (int mt = 0; mt < 4; ++mt) {
#pragma unroll
        for (int r = 0; r < 4; ++r) {
            float part = 0.f;
#pragma unroll
            for (int nt = 0; nt < 4; ++nt) {
                float z = fmaf(acc[mt][nt][r], rsigma, bi[nt]);
                float d = ce[nt] - z;
                part = fmaf(d, d, part);
            }
            part += __shfl_xor(part, 1, 64);
            part += __shfl_xor(part, 2, 64);
            part += __shfl_xor(part, 4, 64);
            part += __shfl_xor(part, 8, 64);
            if (ln == 0) {
                int m = wm * 64 + mt * 16 + quad * 4 + r;
                red[m * 2 + wn] = part;
            }
        }
    }
    __syncthreads();
    if (t < 128) {
        float d2 = red[t * 2] + red[t * 2 + 1];
        out[(size_t)(b0 + t) * C_ + c] = expf(-0.5f * d2);
    }
}

extern "C" void kernel_launch(void* const* d_in, const int* in_sizes, int n_in,
                              void* d_out, int out_size, void* d_ws, size_t ws_size,
                              hipStream_t stream) {
    const float* x  = (const float*)d_in[0];
    const float* W  = (const float*)d_in[1];
    const float* b  = (const float*)d_in[2];
    const float* u  = (const float*)d_in[3];
    const float* cc = (const float*)d_in[4];
    float* out = (float*)d_out;

    _Float16* xh = (_Float16*)d_ws;     // 2,097,152 B (only workspace user now)

    k_prep<<<128, 256, 0, stream>>>(x, xh);
    k_fused<<<416, 256, 0, stream>>>(W, xh, b, cc, u, out);
}

// Round 6
// 212.724 us; speedup vs baseline: 1.0742x; 1.0742x over previous
//
#include <hip/hip_runtime.h>
#include <math.h>

#define B_ 512
#define C_ 100
#define E_ 2048
#define F_ 128
#define NCHUNK 16
#define CHUNKW 128   // k-width per gram block

typedef _Float16 f16x8 __attribute__((ext_vector_type(8)));
typedef float    f32x4 __attribute__((ext_vector_type(4)));

#define AS1q __attribute__((address_space(1)))
#define AS3q __attribute__((address_space(3)))

// async global->LDS DMA, 16 B per lane; LDS dest = wave-uniform base + lane*16
__device__ __forceinline__ void gl_lds16(const void* g, void* lds_base) {
    __builtin_amdgcn_global_load_lds((const AS1q void*)g, (AS3q void*)lds_base, 16, 0, 0);
}

// ---------------- kernel 1: W fp32 -> Wh fp16 conversion + y = W(W^T u) matvecs
// blocks 0..1599: (c = b>>4, chunk = b&15), k-window = chunk*128 +: 128.
//   fp32 W --DMA--> LDS (swizzled). Per 64-col iter:
//     A1: v[e] = sum_f W[f,e]*u[f]   (column sums; block holds all 128 f-rows)
//     conv: LDS fp32 -> fp16 -> Wh   (row registers kept)
//     A2: y_chunk[f] += row_f . v    (from the same registers)
//   ychunks[chunk][c][f] = y_chunk.  sum over chunks in k_main = W(W^T u) = G u.
//   Memory-bound at its ~158 MB stream floor (~30 us). Round-5 lesson: DO NOT
//   fuse the GEMM in here — fusing forces 4x re-staging of the fp32 W tile.
// blocks 1600..1631: x fp32 -> fp16 xh.
__global__ __launch_bounds__(256, 4)
void k_gram(const float* __restrict__ W, _Float16* __restrict__ Wh,
            const float* __restrict__ x, _Float16* __restrict__ xh,
            const float* __restrict__ u, float* __restrict__ ychunks) {
    const int b = blockIdx.x;
    const int t = threadIdx.x;

    if (b >= 1600) {   // ---- x conversion
        const size_t base = (size_t)(b - 1600) * 32768 + t * 8;
#pragma unroll
        for (int it = 0; it < 16; ++it) {
            const size_t idx = base + (size_t)it * 2048;
            float4 a  = *(const float4*)(x + idx);
            float4 bb = *(const float4*)(x + idx + 4);
            f16x8 h;
            h[0] = (_Float16)a.x;  h[1] = (_Float16)a.y;  h[2] = (_Float16)a.z;  h[3] = (_Float16)a.w;
            h[4] = (_Float16)bb.x; h[5] = (_Float16)bb.y; h[6] = (_Float16)bb.z; h[7] = (_Float16)bb.w;
            *(f16x8*)(xh + idx) = h;
        }
        return;
    }

    const int c     = b >> 4;
    const int chunk = b & 15;
    const int w = t >> 6;
    const int l = t & 63;
    const int lrow4 = l >> 4, cs = l & 15;

    __shared__ float Ts[128 * 64];   // 32 KB swizzled fp32 tile
    __shared__ float vs[64];         // v[e] for current 64-col window
    __shared__ float us[128];        // u[f] for this class
    __shared__ float yred[256];      // per-thread y partials

    const float* wbase = W + (size_t)c * F_ * E_ + chunk * CHUNKW;

    // conversion-side constants: thread owns row cr, floats [cb, cb+32)
    const int cr = t >> 1, cb = (t & 1) * 32;
    _Float16* wdst = Wh + ((size_t)c * F_ + cr) * E_ + chunk * CHUNKW + cb;

    if (t < 128) us[t] = u[(size_t)c * F_ + t];

    // A1 assignment: column e = t>>2 (0..63), f-range [(t&3)*32, +32)
    const int ae = t >> 2;
    const int af = (t & 3) * 32;
    const int gch = ae >> 2, el = ae & 3;

    float yacc = 0.f;

#pragma unroll
    for (int it = 0; it < CHUNKW / 64; ++it) {
        const int k0 = it * 64;
#pragma unroll
        for (int qq = 0; qq < 8; ++qq) {
            const int q   = w * 8 + qq;
            const int r   = q * 4 + lrow4;
            const int off = ((cs ^ (r & 15)) << 2);
            gl_lds16(wbase + (size_t)r * E_ + k0 + off, &Ts[q * 256]);
        }
        __syncthreads();   // tile ready (also publishes us[] on it=0)

        // ---- A1: v[e] = sum_f W[f,e] * u[f]  (swizzle-aware column reads)
        {
            float p = 0.f;
#pragma unroll
            for (int j = 0; j < 32; ++j) {
                const int f = af + j;
                p = fmaf(Ts[(f << 6) + (((gch ^ (f & 15)) << 2) | el)], us[f], p);
            }
            p += __shfl_xor(p, 1, 64);
            p += __shfl_xor(p, 2, 64);
            if ((t & 3) == 0) vs[ae] = p;
        }

        // ---- conv: row cr fp32 -> fp16 -> Wh (registers reused by A2)
        f32x4 cv[8];
#pragma unroll
        for (int j = 0; j < 8; ++j) {
            const int g = (cb >> 2) + j;
            cv[j] = *(const f32x4*)&Ts[cr * 64 + ((g ^ (cr & 15)) << 2)];
        }
#pragma unroll
        for (int j = 0; j < 4; ++j) {
            f16x8 h;
            h[0] = (_Float16)cv[2*j][0];   h[1] = (_Float16)cv[2*j][1];
            h[2] = (_Float16)cv[2*j][2];   h[3] = (_Float16)cv[2*j][3];
            h[4] = (_Float16)cv[2*j+1][0]; h[5] = (_Float16)cv[2*j+1][1];
            h[6] = (_Float16)cv[2*j+1][2]; h[7] = (_Float16)cv[2*j+1][3];
            *(f16x8*)(wdst + k0 + j * 8) = h;
        }
        __syncthreads();   // vs ready; Ts fully consumed (next DMA may overwrite)

        // ---- A2: y_chunk[cr] partial += row(cr, cols cb..cb+32) . vs
#pragma unroll
        for (int j = 0; j < 8; ++j) {
            const f32x4 vv = *(const f32x4*)&vs[cb + j * 4];
            yacc = fmaf(cv[j][0], vv[0], yacc);
            yacc = fmaf(cv[j][1], vv[1], yacc);
            yacc = fmaf(cv[j][2], vv[2], yacc);
            yacc = fmaf(cv[j][3], vv[3], yacc);
        }
    }

    yred[cr * 2 + (t & 1)] = yacc;
    __syncthreads();
    if (t < 128)
        ychunks[((size_t)chunk * C_ + c) * F_ + t] = yred[t * 2] + yred[t * 2 + 1];
}

// ---------------- kernel 2: fused fp16 MFMA GEMM + dist2 + exp, rsig inline
// Round-3 XCD map (1-D grid 416): xcd = bid&7, slot = bid>>3,
//   c = xcd*13 + slot>>2, b-tile = slot&3 -> 4 sibling b-tiles of a class on
//   ONE XCD, adjacent dispatch -> Wh slice L2-shared.
// NEW (T3-min + T4-lite): double-buffered LDS; iter k issues the DMA for
// iter k+1 BEFORE computing iter k, with ONE barrier per iter. The compiler's
// auto vmcnt(0)-before-barrier then drains a DMA whose flight time overlapped
// the whole MFMA phase. At ~1.5 blocks/CU there is no TLP to hide the drain
// implicitly (m114), so the explicit prefetch has real headroom here.
// block 256 = 4 waves (2x2); M=128, N=128, BK=64; LDS 64 KB -> 2 blocks/CU.
__global__ __launch_bounds__(256, 2)
void k_main(const _Float16* __restrict__ xh, const _Float16* __restrict__ Wh,
            const float* __restrict__ bias, const float* __restrict__ cent,
            const float* __restrict__ u, const float* __restrict__ ychunks,
            float* __restrict__ out) {
    const int bid  = blockIdx.x;
    const int xcd  = bid & 7;
    const int slot = bid >> 3;
    const int c    = xcd * 13 + (slot >> 2);
    if (c >= C_) return;                       // uniform early-out (16 blocks)
    const int b0 = (slot & 3) * 128;

    const int t  = threadIdx.x;
    const int w  = t >> 6;
    const int l  = t & 63;
    const int wm = w & 1, wn = w >> 1;
    const int ln = l & 15, quad = l >> 4;

    __shared__ _Float16 Xs[2][128 * 64];   // 2 x 16 KB
    __shared__ _Float16 Ws[2][128 * 64];   // 2 x 16 KB
    __shared__ float red2[2][2];
    __shared__ float s_rsig;

    const int lr = l >> 3;
    const int lg = (l & 7) ^ lr;
    // wave w stages X rows [w*32,+32) and W rows [w*32,+32), 4 DMA instrs each
    const _Float16* xsrc = xh + (size_t)(b0 + w * 32 + lr) * E_ + lg * 8;
    const _Float16* wsrc = Wh + ((size_t)c * F_ + w * 32 + lr) * E_ + lg * 8;

    // ---- prologue: issue buffer-0 DMA first, overlap the rsig preamble with it
#pragma unroll
    for (int q = 0; q < 4; ++q)
        gl_lds16(xsrc + (size_t)q * 8 * E_, &Xs[0][(w * 4 + q) * 512]);
#pragma unroll
    for (int q = 0; q < 4; ++q)
        gl_lds16(wsrc + (size_t)q * 8 * E_, &Ws[0][(w * 4 + q) * 512]);

    // ---- inline rsig = sqrt(u.y / y.y),  y[f] = sum_chunk ychunks[chunk][c][f]
    if (t < 128) {
        float yf = 0.f;
#pragma unroll
        for (int ch = 0; ch < NCHUNK; ++ch)
            yf += ychunks[((size_t)ch * C_ + c) * F_ + t];
        float nvp = u[(size_t)c * F_ + t] * yf;
        float tsp = yf * yf;
        for (int off = 32; off; off >>= 1) {
            nvp += __shfl_down(nvp, off, 64);
            tsp += __shfl_down(tsp, off, 64);
        }
        if (l == 0) { red2[w][0] = nvp; red2[w][1] = tsp; }
    }
    __syncthreads();   // red2 ready AND buffer 0 staged (auto vmcnt(0) here)
    if (t == 0) s_rsig = sqrtf((red2[0][0] + red2[1][0]) / (red2[0][1] + red2[1][1]));
    // s_rsig visibility guaranteed by the K-loop barriers below.

    f32x4 acc[4][4];
#pragma unroll
    for (int mt = 0; mt < 4; ++mt)
#pragma unroll
        for (int nt = 0; nt < 4; ++nt) acc[mt][nt] = (f32x4){0.f, 0.f, 0.f, 0.f};

    // epilogue constants hoisted (latency hidden under K-loop)
    float bi[4], ce[4];
#pragma unroll
    for (int nt = 0; nt < 4; ++nt) {
        int f = wn * 64 + nt * 16 + ln;
        bi[nt] = bias[c * F_ + f];
        ce[nt] = cent[c * F_ + f];
    }

    for (int k = 0; k < E_ / 64; ++k) {
        // ---- prefetch iter k+1 into the other buffer (no barrier dependency)
        if (k < E_ / 64 - 1) {
            const int nb = (k + 1) & 1;
            const size_t ko = (size_t)(k + 1) * 64;
#pragma unroll
            for (int q = 0; q < 4; ++q)
                gl_lds16(xsrc + (size_t)q * 8 * E_ + ko, &Xs[nb][(w * 4 + q) * 512]);
#pragma unroll
            for (int q = 0; q < 4; ++q)
                gl_lds16(wsrc + (size_t)q * 8 * E_ + ko, &Ws[nb][(w * 4 + q) * 512]);
        }

        // ---- compute iter k from the current buffer
        const _Float16* Xc = Xs[k & 1];
        const _Float16* Wc = Ws[k & 1];
#pragma unroll
        for (int kk = 0; kk < 64; kk += 32) {
            const int g0 = (kk >> 3) + quad;
            const int sw = (g0 ^ (ln & 7)) * 8;
            f16x8 av[4], bv[4];
#pragma unroll
            for (int mt = 0; mt < 4; ++mt)
                av[mt] = *(const f16x8*)&Xc[(wm * 64 + mt * 16 + ln) * 64 + sw];
#pragma unroll
            for (int nt = 0; nt < 4; ++nt)
                bv[nt] = *(const f16x8*)&Wc[(wn * 64 + nt * 16 + ln) * 64 + sw];
#pragma unroll
            for (int mt = 0; mt < 4; ++mt)
#pragma unroll
                for (int nt = 0; nt < 4; ++nt)
                    acc[mt][nt] = __builtin_amdgcn_mfma_f32_16x16x32_f16(
                        av[mt], bv[nt], acc[mt][nt], 0, 0, 0);
        }
        __syncthreads();   // single barrier/iter: cur reads done + prefetch landed
    }

    const float rsigma = s_rsig;

    float* red = (float*)&Xs[0][0];     // [128][2] floats, post-loop reuse

#pragma unroll
    for (int mt = 0; mt < 4; ++mt) {
#pragma unroll
        for (int r = 0; r < 4; ++r) {
            float part = 0.f;
#pragma unroll
            for (int nt = 0; nt < 4; ++nt) {
                float z = fmaf(acc[mt][nt][r], rsigma, bi[nt]);
                float d = ce[nt] - z;
                part = fmaf(d, d, part);
            }
            part += __shfl_xor(part, 1, 64);
            part += __shfl_xor(part, 2, 64);
            part += __shfl_xor(part, 4, 64);
            part += __shfl_xor(part, 8, 64);
            if (ln == 0) {
                int m = wm * 64 + mt * 16 + quad * 4 + r;
                red[m * 2 + wn] = part;
            }
        }
    }
    __syncthreads();
    if (t < 128) {
        float d2 = red[t * 2] + red[t * 2 + 1];
        out[(size_t)(b0 + t) * C_ + c] = expf(-0.5f * d2);
    }
}

extern "C" void kernel_launch(void* const* d_in, const int* in_sizes, int n_in,
                              void* d_out, int out_size, void* d_ws, size_t ws_size,
                              hipStream_t stream) {
    const float* x  = (const float*)d_in[0];
    const float* W  = (const float*)d_in[1];
    const float* b  = (const float*)d_in[2];
    const float* u  = (const float*)d_in[3];
    const float* cc = (const float*)d_in[4];
    float* out = (float*)d_out;

    // workspace layout (all 16B aligned)
    char* ws = (char*)d_ws;
    _Float16* Wh      = (_Float16*)ws;                                // 52,428,800 B
    _Float16* xh      = (_Float16*)(ws + (size_t)C_ * F_ * E_ * 2);   //  2,097,152 B
    float*    ychunks = (float*)(ws + (size_t)C_ * F_ * E_ * 2 + (size_t)B_ * E_ * 2); // 819,200 B

    k_gram<<<1632, 256, 0, stream>>>(W, Wh, x, xh, u, ychunks);

    k_main<<<416, 256, 0, stream>>>(xh, Wh, b, cc, u, ychunks, out);
}

// Round 7
// 212.057 us; speedup vs baseline: 1.0775x; 1.0031x over previous
//
#include <hip/hip_runtime.h>
#include <math.h>

#define B_ 512
#define C_ 100
#define E_ 2048
#define F_ 128
#define NCHUNK 16
#define CHUNKW 128   // k-width per gram block

typedef _Float16 f16x8 __attribute__((ext_vector_type(8)));
typedef float    f32x4 __attribute__((ext_vector_type(4)));

#define AS1q __attribute__((address_space(1)))
#define AS3q __attribute__((address_space(3)))

// async global->LDS DMA, 16 B per lane; LDS dest = wave-uniform base + lane*16
__device__ __forceinline__ void gl_lds16(const void* g, void* lds_base) {
    __builtin_amdgcn_global_load_lds((const AS1q void*)g, (AS3q void*)lds_base, 16, 0, 0);
}

// ---------------- kernel 1: W fp32 -> Wh fp16 conversion + y = W(W^T u) matvecs
// blocks 0..1599: (c = b>>4, chunk = b&15), k-window = chunk*128 +: 128.
//   fp32 W --DMA--> LDS (swizzled). Per 64-col iter:
//     A1: v[e] = sum_f W[f,e]*u[f]   (column sums; block holds all 128 f-rows)
//     conv: LDS fp32 -> fp16 -> Wh   (row registers kept)
//     A2: y_chunk[f] += row_f . v    (from the same registers)
//   ychunks[chunk][c][f] = y_chunk.  sum over chunks in k_main = W(W^T u) = G u.
//   Memory-bound at its ~160 MB stream floor (~27 us). Round-5 lesson: DO NOT
//   fuse the GEMM in here — fusing forces 4x re-staging of the fp32 W tile.
// blocks 1600..1631: x fp32 -> fp16 xh.
__global__ __launch_bounds__(256, 4)
void k_gram(const float* __restrict__ W, _Float16* __restrict__ Wh,
            const float* __restrict__ x, _Float16* __restrict__ xh,
            const float* __restrict__ u, float* __restrict__ ychunks) {
    const int b = blockIdx.x;
    const int t = threadIdx.x;

    if (b >= 1600) {   // ---- x conversion
        const size_t base = (size_t)(b - 1600) * 32768 + t * 8;
#pragma unroll
        for (int it = 0; it < 16; ++it) {
            const size_t idx = base + (size_t)it * 2048;
            float4 a  = *(const float4*)(x + idx);
            float4 bb = *(const float4*)(x + idx + 4);
            f16x8 h;
            h[0] = (_Float16)a.x;  h[1] = (_Float16)a.y;  h[2] = (_Float16)a.z;  h[3] = (_Float16)a.w;
            h[4] = (_Float16)bb.x; h[5] = (_Float16)bb.y; h[6] = (_Float16)bb.z; h[7] = (_Float16)bb.w;
            *(f16x8*)(xh + idx) = h;
        }
        return;
    }

    const int c     = b >> 4;
    const int chunk = b & 15;
    const int w = t >> 6;
    const int l = t & 63;
    const int lrow4 = l >> 4, cs = l & 15;

    __shared__ float Ts[128 * 64];   // 32 KB swizzled fp32 tile
    __shared__ float vs[64];         // v[e] for current 64-col window
    __shared__ float us[128];        // u[f] for this class
    __shared__ float yred[256];      // per-thread y partials

    const float* wbase = W + (size_t)c * F_ * E_ + chunk * CHUNKW;

    // conversion-side constants: thread owns row cr, floats [cb, cb+32)
    const int cr = t >> 1, cb = (t & 1) * 32;
    _Float16* wdst = Wh + ((size_t)c * F_ + cr) * E_ + chunk * CHUNKW + cb;

    if (t < 128) us[t] = u[(size_t)c * F_ + t];

    // A1 assignment: column e = t>>2 (0..63), f-range [(t&3)*32, +32)
    const int ae = t >> 2;
    const int af = (t & 3) * 32;
    const int gch = ae >> 2, el = ae & 3;

    float yacc = 0.f;

#pragma unroll
    for (int it = 0; it < CHUNKW / 64; ++it) {
        const int k0 = it * 64;
#pragma unroll
        for (int qq = 0; qq < 8; ++qq) {
            const int q   = w * 8 + qq;
            const int r   = q * 4 + lrow4;
            const int off = ((cs ^ (r & 15)) << 2);
            gl_lds16(wbase + (size_t)r * E_ + k0 + off, &Ts[q * 256]);
        }
        __syncthreads();   // tile ready (also publishes us[] on it=0)

        // ---- A1: v[e] = sum_f W[f,e] * u[f]  (swizzle-aware column reads)
        {
            float p = 0.f;
#pragma unroll
            for (int j = 0; j < 32; ++j) {
                const int f = af + j;
                p = fmaf(Ts[(f << 6) + (((gch ^ (f & 15)) << 2) | el)], us[f], p);
            }
            p += __shfl_xor(p, 1, 64);
            p += __shfl_xor(p, 2, 64);
            if ((t & 3) == 0) vs[ae] = p;
        }

        // ---- conv: row cr fp32 -> fp16 -> Wh (registers reused by A2)
        f32x4 cv[8];
#pragma unroll
        for (int j = 0; j < 8; ++j) {
            const int g = (cb >> 2) + j;
            cv[j] = *(const f32x4*)&Ts[cr * 64 + ((g ^ (cr & 15)) << 2)];
        }
#pragma unroll
        for (int j = 0; j < 4; ++j) {
            f16x8 h;
            h[0] = (_Float16)cv[2*j][0];   h[1] = (_Float16)cv[2*j][1];
            h[2] = (_Float16)cv[2*j][2];   h[3] = (_Float16)cv[2*j][3];
            h[4] = (_Float16)cv[2*j+1][0]; h[5] = (_Float16)cv[2*j+1][1];
            h[6] = (_Float16)cv[2*j+1][2]; h[7] = (_Float16)cv[2*j+1][3];
            *(f16x8*)(wdst + k0 + j * 8) = h;
        }
        __syncthreads();   // vs ready; Ts fully consumed (next DMA may overwrite)

        // ---- A2: y_chunk[cr] partial += row(cr, cols cb..cb+32) . vs
#pragma unroll
        for (int j = 0; j < 8; ++j) {
            const f32x4 vv = *(const f32x4*)&vs[cb + j * 4];
            yacc = fmaf(cv[j][0], vv[0], yacc);
            yacc = fmaf(cv[j][1], vv[1], yacc);
            yacc = fmaf(cv[j][2], vv[2], yacc);
            yacc = fmaf(cv[j][3], vv[3], yacc);
        }
    }

    yred[cr * 2 + (t & 1)] = yacc;
    __syncthreads();
    if (t < 128)
        ychunks[((size_t)chunk * C_ + c) * F_ + t] = yred[t * 2] + yred[t * 2 + 1];
}

// ---------------- kernel 2: fused fp16 MFMA GEMM + dist2 + exp, rsig inline
// Round-3 XCD map (1-D grid 416): xcd = bid&7, slot = bid>>3,
//   c = xcd*13 + slot>>2, b-tile = slot&3 -> 4 sibling b-tiles of a class on
//   ONE XCD, adjacent dispatch -> Wh slice L2-shared.
// T4 counted-vmcnt dbuf (round-6 lesson: __syncthreads() emits vmcnt(0)
// BEFORE the barrier, draining the prefetch -> no overlap. Raw s_barrier +
// "s_waitcnt vmcnt(8)" keeps the 8 prefetch loads in flight; their latency
// hides under the current iter's 32 MFMA + ds_reads).
//   loop k:  STAGE(buf[k+1])  ->  vmcnt(8) [buf[k] landed, prefetch flying]
//            s_barrier  ->  MFMA from buf[k]  ->  s_barrier [reads done
//            before iter k+1 overwrites buf[k]]
// block 256 = 4 waves (2x2); M=128, N=128, BK=64; LDS 64 KB -> 2 blocks/CU.
__global__ __launch_bounds__(256, 2)
void k_main(const _Float16* __restrict__ xh, const _Float16* __restrict__ Wh,
            const float* __restrict__ bias, const float* __restrict__ cent,
            const float* __restrict__ u, const float* __restrict__ ychunks,
            float* __restrict__ out) {
    const int bid  = blockIdx.x;
    const int xcd  = bid & 7;
    const int slot = bid >> 3;
    const int c    = xcd * 13 + (slot >> 2);
    if (c >= C_) return;                       // uniform early-out (16 blocks)
    const int b0 = (slot & 3) * 128;

    const int t  = threadIdx.x;
    const int w  = t >> 6;
    const int l  = t & 63;
    const int wm = w & 1, wn = w >> 1;
    const int ln = l & 15, quad = l >> 4;

    __shared__ _Float16 Xs[2][128 * 64];   // 2 x 16 KB
    __shared__ _Float16 Ws[2][128 * 64];   // 2 x 16 KB
    __shared__ float red2[2][2];
    __shared__ float s_rsig;

    const int lr = l >> 3;
    const int lg = (l & 7) ^ lr;
    // wave w stages X rows [w*32,+32) and W rows [w*32,+32), 4 DMA instrs each
    const _Float16* xsrc = xh + (size_t)(b0 + w * 32 + lr) * E_ + lg * 8;
    const _Float16* wsrc = Wh + ((size_t)c * F_ + w * 32 + lr) * E_ + lg * 8;

    // epilogue constants FIRST (older than all staging loads in vmcnt order)
    float bi[4], ce[4];
#pragma unroll
    for (int nt = 0; nt < 4; ++nt) {
        int f = wn * 64 + nt * 16 + ln;
        bi[nt] = bias[c * F_ + f];
        ce[nt] = cent[c * F_ + f];
    }

    // ---- prologue: stage buffer 0; its drain happens at the preamble barrier
#pragma unroll
    for (int q = 0; q < 4; ++q)
        gl_lds16(xsrc + (size_t)q * 8 * E_, &Xs[0][(w * 4 + q) * 512]);
#pragma unroll
    for (int q = 0; q < 4; ++q)
        gl_lds16(wsrc + (size_t)q * 8 * E_, &Ws[0][(w * 4 + q) * 512]);

    // ---- inline rsig = sqrt(u.y / y.y),  y[f] = sum_chunk ychunks[chunk][c][f]
    if (t < 128) {
        float yf = 0.f;
#pragma unroll
        for (int ch = 0; ch < NCHUNK; ++ch)
            yf += ychunks[((size_t)ch * C_ + c) * F_ + t];
        float nvp = u[(size_t)c * F_ + t] * yf;
        float tsp = yf * yf;
        for (int off = 32; off; off >>= 1) {
            nvp += __shfl_down(nvp, off, 64);
            tsp += __shfl_down(tsp, off, 64);
        }
        if (l == 0) { red2[w][0] = nvp; red2[w][1] = tsp; }
    }
    __syncthreads();   // red2 ready AND buffer 0 staged (vmcnt(0) drain here, once)
    if (t == 0) s_rsig = sqrtf((red2[0][0] + red2[1][0]) / (red2[0][1] + red2[1][1]));
    // s_rsig visibility guaranteed by the K-loop barriers below.

    f32x4 acc[4][4];
#pragma unroll
    for (int mt = 0; mt < 4; ++mt)
#pragma unroll
        for (int nt = 0; nt < 4; ++nt) acc[mt][nt] = (f32x4){0.f, 0.f, 0.f, 0.f};

    const int NT = E_ / 64;   // 32
    for (int k = 0; k < NT; ++k) {
        const int cur = k & 1;

        // ---- prefetch iter k+1 into the other buffer, then counted wait:
        // vmcnt(8) = buf[cur]'s 8 loads landed; the 8 just-issued stay in flight.
        if (k + 1 < NT) {
            const size_t ko = (size_t)(k + 1) * 64;
            _Float16* xd = &Xs[cur ^ 1][0];
            _Float16* wd = &Ws[cur ^ 1][0];
#pragma unroll
            for (int q = 0; q < 4; ++q)
                gl_lds16(xsrc + (size_t)q * 8 * E_ + ko, xd + (w * 4 + q) * 512);
#pragma unroll
            for (int q = 0; q < 4; ++q)
                gl_lds16(wsrc + (size_t)q * 8 * E_ + ko, wd + (w * 4 + q) * 512);
            asm volatile("s_waitcnt vmcnt(8)" ::: "memory");
        } else {
            asm volatile("s_waitcnt vmcnt(0)" ::: "memory");
        }
        __builtin_amdgcn_s_barrier();   // all waves: buf[cur] fully staged

        // ---- compute iter k from buf[cur]
        const _Float16* Xc = &Xs[cur][0];
        const _Float16* Wc = &Ws[cur][0];
#pragma unroll
        for (int kk = 0; kk < 64; kk += 32) {
            const int g0 = (kk >> 3) + quad;
            const int sw = (g0 ^ (ln & 7)) * 8;
            f16x8 av[4], bv[4];
#pragma unroll
            for (int mt = 0; mt < 4; ++mt)
                av[mt] = *(const f16x8*)&Xc[(wm * 64 + mt * 16 + ln) * 64 + sw];
#pragma unroll
            for (int nt = 0; nt < 4; ++nt)
                bv[nt] = *(const f16x8*)&Wc[(wn * 64 + nt * 16 + ln) * 64 + sw];
#pragma unroll
            for (int mt = 0; mt < 4; ++mt)
#pragma unroll
                for (int nt = 0; nt < 4; ++nt)
                    acc[mt][nt] = __builtin_amdgcn_mfma_f32_16x16x32_f16(
                        av[mt], bv[nt], acc[mt][nt], 0, 0, 0);
        }
        __builtin_amdgcn_s_barrier();   // reads of buf[cur] done before overwrite
    }

    const float rsigma = s_rsig;

    float* red = (float*)&Xs[0][0];     // [128][2] floats, post-loop reuse

#pragma unroll
    for (int mt = 0; mt < 4; ++mt) {
#pragma unroll
        for (int r = 0; r < 4; ++r) {
            float part = 0.f;
#pragma unroll
            for (int nt = 0; nt < 4; ++nt) {
                float z = fmaf(acc[mt][nt][r], rsigma, bi[nt]);
                float d = ce[nt] - z;
                part = fmaf(d, d, part);
            }
            part += __shfl_xor(part, 1, 64);
            part += __shfl_xor(part, 2, 64);
            part += __shfl_xor(part, 4, 64);
            part += __shfl_xor(part, 8, 64);
            if (ln == 0) {
                int m = wm * 64 + mt * 16 + quad * 4 + r;
                red[m * 2 + wn] = part;
            }
        }
    }
    __syncthreads();
    if (t < 128) {
        float d2 = red[t * 2] + red[t * 2 + 1];
        out[(size_t)(b0 + t) * C_ + c] = expf(-0.5f * d2);
    }
}

extern "C" void kernel_launch(void* const* d_in, const int* in_sizes, int n_in,
                              void* d_out, int out_size, void* d_ws, size_t ws_size,
                              hipStream_t stream) {
    const float* x  = (const float*)d_in[0];
    const float* W  = (const float*)d_in[1];
    const float* b  = (const float*)d_in[2];
    const float* u  = (const float*)d_in[3];
    const float* cc = (const float*)d_in[4];
    float* out = (float*)d_out;

    // workspace layout (all 16B aligned)
    char* ws = (char*)d_ws;
    _Float16* Wh      = (_Float16*)ws;                                // 52,428,800 B
    _Float16* xh      = (_Float16*)(ws + (size_t)C_ * F_ * E_ * 2);   //  2,097,152 B
    float*    ychunks = (float*)(ws + (size_t)C_ * F_ * E_ * 2 + (size_t)B_ * E_ * 2); // 819,200 B

    k_gram<<<1632, 256, 0, stream>>>(W, Wh, x, xh, u, ychunks);

    k_main<<<416, 256, 0, stream>>>(xh, Wh, b, cc, u, ychunks, out);
}